// Round 16
// baseline (127.950 us; speedup 1.0000x reference)
//
#include <hip/hip_runtime.h>
#include <hip/hip_bf16.h>

// Problem constants (from reference setup_inputs)
#define BB 2
#define NH 4
#define NN 2304
#define DIM 64
#define DH 8
#define HID 32
#define KN 314   // neighbors per point

// Workspace layout (float offsets):
#define QKV_OFF 0
#define QKV_SZ  (BB*NN*96)
#define A_OFF   (QKV_OFF + QKV_SZ)
#define A_SZ    (BB*NH*NN*HID)
#define BK_OFF  (A_OFF + A_SZ)
#define BK_SZ   (BB*NH*NN*HID)
#define V_OFF   (BK_OFF + BK_SZ)
#define V_SZ    (BB*NH*NN*DH)
#define DEN_OFF (V_OFF + V_SZ)
#define DEN_SZ  (BB*NH*KN*DH)
#define AGG_OFF (DEN_OFF + DEN_SZ)
#define AGG_SZ  (BB*NH*NN*DH)
#define NUM_OFF (AGG_OFF + AGG_SZ)                 // bf16 num buffer: [bh][i][j][d]
#define NUM_ELTS ((size_t)BB*NH*NN*KN*DH)          // 46.3M bf16 = 92.6 MB
#define BHF_OFF (NUM_OFF + NUM_ELTS/2)             // fp16 copy of Bk: [bh][p][e]
#define AHF_OFF (BHF_OFF + BK_SZ/2)                // fp16 copy of A:  [bh][p][e]
#define WS_NEED_BYTES ((size_t)(AHF_OFF + A_SZ/2)*4)

typedef float v2f __attribute__((ext_vector_type(2)));
typedef __attribute__((ext_vector_type(8))) short bf16x8;
typedef __attribute__((ext_vector_type(4))) float f32x4;
typedef _Float16 fp16x8 __attribute__((ext_vector_type(8)));
typedef _Float16 h2 __attribute__((ext_vector_type(2)));
#define SWZ(x, imm) __int_as_float(__builtin_amdgcn_ds_swizzle(__float_as_int(x), imm))

union U16x8 { uint4 q; h2 h[4]; fp16x8 v; };

static __device__ __forceinline__ float bfb(unsigned short u){
    return __uint_as_float(((unsigned)u) << 16);
}
// HW packed convert: dst.lo = bf16(a), dst.hi = bf16(b)
static __device__ __forceinline__ unsigned cvtpk(float a, float b){
    unsigned r;
    asm("v_cvt_pk_bf16_f32 %0, %1, %2" : "=v"(r) : "v"(a), "v"(b));
    return r;
}
static __device__ __forceinline__ unsigned short f2h_bits(float f){
    _Float16 h = (_Float16)f;
    unsigned short u; __builtin_memcpy(&u, &h, 2); return u;
}

// ---------------- K1: qkv = x @ w_qkv ----------------
__global__ void qkv_kernel(const float* __restrict__ x, const float* __restrict__ w_qkv, float* ws){
    int t = blockIdx.x*256 + threadIdx.x;
    if (t >= BB*NN*96) return;
    int c = t % 96;
    int p = (t / 96) % NN;
    int b = t / (96*NN);
    const float* xr = x + (b*NN + p)*DIM;
    float acc = 0.f;
    #pragma unroll 8
    for (int dd=0; dd<DIM; dd++)
        acc = fmaf(xr[dd], w_qkv[dd*96 + c], acc);
    ws[QKV_OFF + (b*NN + p)*96 + c] = acc;
}

// ---------------- K2: A = w1.q + b1 ; Bk = w1.k ; fp16 copies ; V copy ----------------
__global__ void ab_kernel(const float* __restrict__ w1, const float* __restrict__ b1, float* ws){
    int t = blockIdx.x*256 + threadIdx.x;
    if (t >= BB*NH*NN*HID) return;
    int e  = t % HID;
    int p  = (t / HID) % NN;
    int hh = (t / (HID*NN)) % NH;
    int b  = t / (HID*NN*NH);
    const float* qkv = ws + QKV_OFF + (b*NN + p)*96;
    const float* w1r = w1 + (hh*HID + e)*DH;
    float sa = b1[hh*HID + e];
    float sb = 0.f;
    #pragma unroll
    for (int d=0; d<DH; d++){
        float wv = w1r[d];
        sa = fmaf(wv, qkv[hh*DH + d],      sa);
        sb = fmaf(wv, qkv[32 + hh*DH + d], sb);
    }
    int base = ((b*NH + hh)*NN + p);
    ws[A_OFF  + base*HID + e] = sa;
    ws[BK_OFF + base*HID + e] = sb;
    ((unsigned short*)(ws + BHF_OFF))[(size_t)base*HID + e] = f2h_bits(sb);
    ((unsigned short*)(ws + AHF_OFF))[(size_t)base*HID + e] = f2h_bits(sa);
    if (e < DH)
        ws[V_OFF + base*DH + e] = qkv[64 + hh*DH + e];
}

// ---------------- K3 (big path): MFMA pass1, fp16 fragments, 2-deep B prefetch ----------------
// sim^T[d,j] = w2 . relu(A[i]-B[p_j])^T via mfma_f32_16x16x32_f16(w2frag, relufrag, c).
// num[bh][i][j][d] bf16: per-lane 4 d's contiguous -> one uint2 store per i.
// grid (20,12,8) = 1920 blocks (7.5/CU). bh = lin&7 = XCD; jt adjacent in dispatch.
__global__ __launch_bounds__(256) void pass1_mfma(const int* __restrict__ idx,
                                                  const float* __restrict__ w2,
                                                  const float* __restrict__ b2, float* ws){
    int lin = blockIdx.x + 20*(blockIdx.y + 12*blockIdx.z);
    int bh  = lin & 7;
    int rest = lin >> 3;          // 0..239
    int jt  = rest % 20;          // adjacent dispatch => adjacent jt
    int yy  = rest / 20;          // 0..11
    int hh  = bh & (NH-1);
    int w = threadIdx.x >> 6, lane = threadIdx.x & 63;
    int n  = lane & 15;    // MFMA col = j index within tile
    int kg = lane >> 4;    // e-slice group; C rows d = kg*4..+3
    int strip = yy*4 + w;  // 0..47
    int i0 = strip*48;

    const float LG2E = 1.44269504088896340736f;
    U16x8 bfr;   // w2 fragment (A-operand rows d=n), fp16, scaled by log2e
    #pragma unroll
    for (int tt=0; tt<8; tt++){
        float wvv = (n < DH) ? w2[(hh*DH + n)*HID + kg*8 + tt]*LG2E : 0.f;
        bfr.v[tt] = (_Float16)wvv;
    }
    // C-init: row d = kg*4+r gets b2[d]*LG2E (rows >= DH are padding)
    f32x4 cinit;
    #pragma unroll
    for (int r=0; r<4; r++){
        int d = kg*4 + r;
        cinit[r] = (d < DH) ? b2[hh*DH + d]*LG2E : 0.f;
    }

    int jrow = jt*16 + n;                 // this lane's j (B-operand col & C col)
    int jj = jrow < KN ? jrow : (KN-1);
    bool stok = (jrow < KN) && (kg < 2);  // lanes holding real (j,d) results

    const unsigned short* Ahf = (const unsigned short*)(ws + AHF_OFF) + (size_t)bh*NN*HID;
    const unsigned short* Bhf = (const unsigned short*)(ws + BHF_OFF) + (size_t)bh*NN*HID;
    const int* idxp = idx + (size_t)i0*KN + jj;
    const unsigned short* ap = Ahf + (size_t)i0*HID + kg*8;

    unsigned short* numb = (unsigned short*)(ws + NUM_OFF);
    size_t nb = (((size_t)bh*NN + i0)*KN + jj)*DH + kg*4;
    const size_t NPI = (size_t)KN*DH;   // shorts per i

    f32x4 den; den[0]=0.f; den[1]=0.f; den[2]=0.f; den[3]=0.f;
    const h2 zz = { (_Float16)0.f, (_Float16)0.f };

    // pipeline: B two iterations ahead, p three iterations ahead
    int p0 = idxp[0], p1 = idxp[KN]; idxp += 2*KN;           // t=0
    uint4 Bc0 = *(const uint4*)(Bhf + (size_t)p0*HID + kg*8);
    uint4 Bc1 = *(const uint4*)(Bhf + (size_t)p1*HID + kg*8);
    p0 = idxp[0]; p1 = idxp[KN]; idxp += 2*KN;               // t=1
    uint4 Bn0 = *(const uint4*)(Bhf + (size_t)p0*HID + kg*8);
    uint4 Bn1 = *(const uint4*)(Bhf + (size_t)p1*HID + kg*8);
    p0 = idxp[0]; p1 = idxp[KN]; idxp += 2*KN;               // t=2

    for (int ii=0; ii<48; ii+=2){
        U16x8 Ah0, Ah1;
        Ah0.q = *(const uint4*)ap;
        Ah1.q = *(const uint4*)(ap + HID);
        ap += 2*HID;

        uint4 Bf0 = Bc0, Bf1 = Bc1;
        if (ii < 44){
            Bf0 = *(const uint4*)(Bhf + (size_t)p0*HID + kg*8);
            Bf1 = *(const uint4*)(Bhf + (size_t)p1*HID + kg*8);
        }
        if (ii < 42){ p0 = idxp[0]; p1 = idxp[KN]; idxp += 2*KN; }

        // fp16 packed fragment build: 4 pk_sub + 4 pk_max per i
        U16x8 Bu0, Bu1, af0, af1;
        Bu0.q = Bc0; Bu1.q = Bc1;
        #pragma unroll
        for (int k=0; k<4; k++){
            h2 d0h = Ah0.h[k] - Bu0.h[k];
            af0.h[k] = __builtin_elementwise_max(d0h, zz);
            h2 d1h = Ah1.h[k] - Bu1.h[k];
            af1.h[k] = __builtin_elementwise_max(d1h, zz);
        }

        // swapped operands: D[d, j] = w2 x relu^T + C
        f32x4 d0 = __builtin_amdgcn_mfma_f32_16x16x32_f16(bfr.v, af0.v, cinit, 0, 0, 0);
        f32x4 d1 = __builtin_amdgcn_mfma_f32_16x16x32_f16(bfr.v, af1.v, cinit, 0, 0, 0);

        float e00 = exp2f(d0[0]), e01 = exp2f(d0[1]), e02 = exp2f(d0[2]), e03 = exp2f(d0[3]);
        float e10 = exp2f(d1[0]), e11 = exp2f(d1[1]), e12 = exp2f(d1[2]), e13 = exp2f(d1[3]);
        den[0] += e00 + e10; den[1] += e01 + e11;
        den[2] += e02 + e12; den[3] += e03 + e13;

        // one uint2 (4 bf16 d-values) store per i per lane
        if (stok){
            uint2 s0; s0.x = cvtpk(e00, e01); s0.y = cvtpk(e02, e03);
            uint2 s1; s1.x = cvtpk(e10, e11); s1.y = cvtpk(e12, e13);
            *(uint2*)(numb + nb)       = s0;
            *(uint2*)(numb + nb + NPI) = s1;
        }
        nb += 2*NPI;

        Bc0 = Bn0; Bc1 = Bn1; Bn0 = Bf0; Bn1 = Bf1;
    }

    if (stok){
        float* denp = ws + DEN_OFF + ((size_t)bh*KN + jrow)*DH + kg*4;
        #pragma unroll
        for (int r2=0; r2<4; r2++)
            atomicAdd(denp + r2, den[r2]);
    }
}

// ---------------- K3.5 (small path only): invert den in place ----------------
__global__ void invden_kernel(float* ws){
    int t = blockIdx.x*256 + threadIdx.x;
    if (t < DEN_SZ){
        float* d = ws + DEN_OFF;
        d[t] = 1.0f / d[t];
    }
}

// ---------------- K4-fast: agg[i,d] = sum_j num[i,j,d]*inv(den[j,d])*v[p,d] ----------------
// grid: (144, NH, BB); block 512 = 8 waves, 2 i per wave; v,m one sg ahead, p two ahead.
__global__ __launch_bounds__(512) void pass2f_kernel(const int* __restrict__ idx, float* ws){
    int hh = blockIdx.y, b = blockIdx.z;
    int w = threadIdx.x >> 6, lane = threadIdx.x & 63;
    int g = lane >> 3, dd = lane & 7;
    int bh = b*NH + hh;

    __shared__ float invs[KN*DH];
    {
        const float* den = ws + DEN_OFF + (size_t)bh*KN*DH;
        for (int t = threadIdx.x; t < KN*DH; t += 512) invs[t] = 1.0f / den[t];
    }
    __syncthreads();

    const float* Vbuf = ws + V_OFF + (size_t)bh*NN*DH;
    float* agg = ws + AGG_OFF + (size_t)bh*NN*DH;

    int i0 = blockIdx.x*16 + w*2;
    const unsigned short* num0 = (const unsigned short*)(ws + NUM_OFF)
                                 + ((size_t)bh*NN + i0)*KN*DH + dd;
    const unsigned short* num1 = num0 + (size_t)KN*DH;
    const int* ix0 = idx + (size_t)i0*KN;
    const int* ix1 = ix0 + KN;

    // pipeline: p two sg ahead; v,m one sg ahead (current values ready at loop top)
    int pc0 = ix0[g], pc1 = ix1[g];                     // p for sg=0
    float vc0 = Vbuf[(size_t)pc0*DH + dd];
    float vc1 = Vbuf[(size_t)pc1*DH + dd];
    float mc0 = bfb(num0[g*DH]), mc1 = bfb(num1[g*DH]); // m,v for sg=0
    int pn0 = ix0[8 + g], pn1 = ix1[8 + g];             // p for sg=1

    float acc0 = 0.f, acc1 = 0.f;

    for (int sg=0; sg<40; sg++){
        int jc = sg*8 + g;
        bool valid = jc < KN;
        int jcc = valid ? jc : (KN-1);
        float iv = invs[jcc*DH + dd];

        float vn0, vn1, mn0, mn1;
        if (sg < 39){
            // prefetch v,m for sg+1 using pn (fetched 2 iters ago)
            vn0 = Vbuf[(size_t)pn0*DH + dd];
            vn1 = Vbuf[(size_t)pn1*DH + dd];
            int jn = jc + 8; int jjn = jn < KN ? jn : (KN-1);
            mn0 = bfb(num0[(size_t)jjn*DH]);
            mn1 = bfb(num1[(size_t)jjn*DH]);
            if (sg < 38){
                int jn2 = jc + 16; int jj2 = jn2 < KN ? jn2 : (KN-1);
                pn0 = ix0[jj2]; pn1 = ix1[jj2];
            }
        }

        float w0 = valid ? mc0 * iv : 0.f;
        float w1 = valid ? mc1 * iv : 0.f;
        acc0 = fmaf(w0, vc0, acc0);
        acc1 = fmaf(w1, vc1, acc1);

        if (sg < 39){ vc0 = vn0; vc1 = vn1; mc0 = mn0; mc1 = mn1; }
    }
    acc0 += __shfl_xor(acc0, 8, 64);
    acc0 += __shfl_xor(acc0, 16, 64);
    acc0 += __shfl_xor(acc0, 32, 64);
    acc1 += __shfl_xor(acc1, 8, 64);
    acc1 += __shfl_xor(acc1, 16, 64);
    acc1 += __shfl_xor(acc1, 32, 64);
    if (g == 0){
        agg[(size_t)i0*DH + dd]     = acc0;
        agg[(size_t)(i0+1)*DH + dd] = acc1;
    }
}

// ================= fallback path (small ws): proven VALU kernels =================
__device__ __forceinline__ void load_w2p(const float* __restrict__ w2, int hh, int dd,
                                         v2f w2a[8], v2f w2b[8]){
    #pragma unroll
    for (int m=0; m<8; m++){
        int d = dd ^ (((m&1)<<2) | (m&2) | ((m>>2)&1));
        const float* wp = w2 + (hh*DH + d)*HID + 4*dd;
        v2f a; a.x = wp[0]; a.y = wp[1];
        v2f b; b.x = wp[2]; b.y = wp[3];
        w2a[m] = a; w2b[m] = b;
    }
}
__device__ __forceinline__ float butterfly8p(float pr[8]){
    float q0 = pr[0] + SWZ(pr[4], 0x041F);
    float q1 = pr[1] + SWZ(pr[5], 0x041F);
    float q2 = pr[2] + SWZ(pr[6], 0x041F);
    float q3 = pr[3] + SWZ(pr[7], 0x041F);
    float r0 = q0 + SWZ(q2, 0x081F);
    float r1 = q1 + SWZ(q3, 0x081F);
    return r0 + SWZ(r1, 0x101F);
}
__global__ __launch_bounds__(256, 4) void pass1_small(const int* __restrict__ idx,
                                                      const float* __restrict__ w2,
                                                      const float* __restrict__ b2, float* ws){
    int sgic = blockIdx.x, hh = blockIdx.y, b = blockIdx.z;
    int sg = sgic >> 4, ic = sgic & 15;
    int w = threadIdx.x >> 6, lane = threadIdx.x & 63;
    int g = lane >> 3, dd = lane & 7;
    int j = sg*8 + g;
    bool jv = (j < KN);
    int jj = jv ? j : (KN-1);
    int bh = b*NH + hh;

    v2f w2a[8], w2b[8];
    load_w2p(w2, hh, dd, w2a, w2b);
    float b2v = b2[hh*DH + dd];

    const float* Abuf = ws + A_OFF  + (size_t)bh*NN*HID + 4*dd;
    const float* Bbuf = ws + BK_OFF + (size_t)bh*NN*HID + 4*dd;
    const int* idxc = idx + jj;

    float den_acc = 0.f;
    int i0 = ic*144 + w*36;
    for (int ii=0; ii<36; ii++){
        int i = i0 + ii;
        int p = idxc[(size_t)i*KN];
        float4 avv = *(const float4*)(Abuf + (size_t)i*HID);
        float4 bvv = *(const float4*)(Bbuf + (size_t)p*HID);
        v2f a0; a0.x=avv.x; a0.y=avv.y;
        v2f a1; a1.x=avv.z; a1.y=avv.w;
        v2f c0; c0.x=bvv.x; c0.y=bvv.y;
        v2f c1; c1.x=bvv.z; c1.y=bvv.w;
        v2f z;  z.x=0.f; z.y=0.f;
        v2f r0 = __builtin_elementwise_max(a0-c0, z);
        v2f r1 = __builtin_elementwise_max(a1-c1, z);
        float pr[8];
        #pragma unroll
        for (int m=0; m<8; m++){
            v2f t = w2a[m]*r0;
            t = __builtin_elementwise_fma(w2b[m], r1, t);
            pr[m] = t.x + t.y;
        }
        float sim = butterfly8p(pr) + b2v;
        den_acc += __expf(sim);
    }
    if (!jv) den_acc = 0.f;

    __shared__ float red[256];
    red[threadIdx.x] = den_acc;
    __syncthreads();
    if (w == 0 && jv){
        float s = red[lane] + red[lane+64] + red[lane+128] + red[lane+192];
        atomicAdd(ws + DEN_OFF + ((size_t)bh*KN + j)*DH + dd, s);
    }
}
__device__ __forceinline__ void load_w2s(const float* __restrict__ w2, int hh, int dd, float w2s[8][4]){
    #pragma unroll
    for (int m=0; m<8; m++){
        int d = ((m&1)<<2) | (m&2) | ((m>>2)&1);
        const float* wp = w2 + (hh*DH + d)*HID + 4*dd;
        w2s[m][0]=wp[0]; w2s[m][1]=wp[1]; w2s[m][2]=wp[2]; w2s[m][3]=wp[3];
    }
}
__device__ __forceinline__ float butterfly8(float pr[8], int dd){
    int b0 = dd&1, b1 = (dd>>1)&1, b2b = (dd>>2)&1;
    float q[4];
    #pragma unroll
    for (int t=0; t<4; t++){
        float send = pr[4*(1-b0)+t];
        float recv = __shfl_xor(send, 1, 64);
        q[t] = pr[4*b0+t] + recv;
    }
    float r[2];
    #pragma unroll
    for (int t=0; t<2; t++){
        float send = q[2*(1-b1)+t];
        float recv = __shfl_xor(send, 2, 64);
        r[t] = q[2*b1+t] + recv;
    }
    float send = r[1-b2b];
    float recv = __shfl_xor(send, 4, 64);
    return r[b2b] + recv;
}
__global__ __launch_bounds__(256) void pass2_kernel(const int* __restrict__ idx,
                                                    const float* __restrict__ w2,
                                                    const float* __restrict__ b2, float* ws){
    int ic = blockIdx.x, hh = blockIdx.y, b = blockIdx.z;
    int w = threadIdx.x >> 6, lane = threadIdx.x & 63;
    int g = lane >> 3, dd = lane & 7;

    float w2s[8][4];
    load_w2s(w2, hh, dd, w2s);
    float b2v = b2[hh*DH + dd];

    const float* Abuf = ws + A_OFF  + (size_t)(b*NH + hh)*NN*HID;
    const float* Bbuf = ws + BK_OFF + (size_t)(b*NH + hh)*NN*HID;
    const float* Vbuf = ws + V_OFF  + (size_t)(b*NH + hh)*NN*DH;
    const float* invd = ws + DEN_OFF + (size_t)(b*NH + hh)*KN*DH;
    float*       agg  = ws + AGG_OFF + (size_t)(b*NH + hh)*NN*DH;

    int i0 = ic*8 + w*2;
    #pragma unroll
    for (int ii=0; ii<2; ii++){
        int i = i0 + ii;
        float4 av = *(const float4*)(Abuf + (size_t)i*HID + 4*dd);
        float acc = 0.f;
        for (int sg=0; sg<40; sg++){
            int j = sg*8 + g;
            bool jvv = (j < KN);
            int jj = jvv ? j : (KN-1);
            int p = idx[i*KN + jj];
            float4 bv = *(const float4*)(Bbuf + (size_t)p*HID + 4*dd);
            float r0 = fmaxf(av.x-bv.x, 0.f), r1 = fmaxf(av.y-bv.y, 0.f);
            float r2 = fmaxf(av.z-bv.z, 0.f), r3 = fmaxf(av.w-bv.w, 0.f);
            float pr[8];
            #pragma unroll
            for (int m=0; m<8; m++)
                pr[m] = fmaf(w2s[m][0],r0, fmaf(w2s[m][1],r1, fmaf(w2s[m][2],r2, w2s[m][3]*r3)));
            float sim = butterfly8(pr, dd) + b2v;
            float attn = jvv ? (__expf(sim) * invd[(size_t)jj*DH + dd]) : 0.f;
            acc = fmaf(attn, Vbuf[(size_t)p*DH + dd], acc);
        }
        acc += __shfl_xor(acc, 8, 64);
        acc += __shfl_xor(acc, 16, 64);
        acc += __shfl_xor(acc, 32, 64);
        if (g == 0) agg[(size_t)i*DH + dd] = acc;
    }
}

// ---------------- K5: out = agg @ w_out + b_out ----------------
__global__ void out_kernel(const float* __restrict__ w_out, const float* __restrict__ b_out,
                           const float* __restrict__ ws, float* __restrict__ out){
    int t = blockIdx.x*256 + threadIdx.x;
    if (t >= BB*NN*DIM) return;
    int c = t % DIM;
    int p = (t / DIM) % NN;
    int b = t / (DIM*NN);
    const float* agg = ws + AGG_OFF;
    float s = b_out[c];
    #pragma unroll
    for (int f=0; f<32; f++){
        int hh = f >> 3, d = f & 7;
        s = fmaf(agg[(((size_t)(b*NH + hh)*NN) + p)*DH + d], w_out[f*DIM + c], s);
    }
    out[t] = s;
}

extern "C" void kernel_launch(void* const* d_in, const int* in_sizes, int n_in,
                              void* d_out, int out_size, void* d_ws, size_t ws_size,
                              hipStream_t stream){
    const float* x     = (const float*)d_in[0];
    const int*   idx   = (const int*)d_in[1];
    const float* w_qkv = (const float*)d_in[2];
    const float* w1    = (const float*)d_in[3];
    const float* b1    = (const float*)d_in[4];
    const float* w2    = (const float*)d_in[5];
    const float* b2    = (const float*)d_in[6];
    const float* w_out = (const float*)d_in[7];
    const float* b_out = (const float*)d_in[8];
    float* ws  = (float*)d_ws;
    float* out = (float*)d_out;

    bool big = (ws_size >= WS_NEED_BYTES);

    hipMemsetAsync(ws + DEN_OFF, 0, DEN_SZ*sizeof(float), stream);

    qkv_kernel<<<(BB*NN*96 + 255)/256, 256, 0, stream>>>(x, w_qkv, ws);
    ab_kernel <<<(BB*NH*NN*HID + 255)/256, 256, 0, stream>>>(w1, b1, ws);
    if (big){
        pass1_mfma<<<dim3(20, 12, 8), 256, 0, stream>>>(idx, w2, b2, ws);
        pass2f_kernel<<<dim3(144, NH, BB), 512, 0, stream>>>(idx, ws);
    } else {
        pass1_small<<<dim3(640, NH, BB), 256, 0, stream>>>(idx, w2, b2, ws);
        invden_kernel<<<(DEN_SZ + 255)/256, 256, 0, stream>>>(ws);
        pass2_kernel<<<dim3(288, NH, BB), 256, 0, stream>>>(idx, w2, b2, ws);
    }
    out_kernel<<<(BB*NN*DIM + 255)/256, 256, 0, stream>>>(w_out, b_out, ws, out);
}

// Round 17
// 118.800 us; speedup vs baseline: 1.0770x; 1.0770x over previous
//
#include <hip/hip_runtime.h>
#include <hip/hip_bf16.h>

// Problem constants (from reference setup_inputs)
#define BB 2
#define NH 4
#define NN 2304
#define DIM 64
#define DH 8
#define HID 32
#define KN 314   // neighbors per point

// Workspace layout (float offsets):
#define QKV_OFF 0
#define QKV_SZ  (BB*NN*96)
#define A_OFF   (QKV_OFF + QKV_SZ)
#define A_SZ    (BB*NH*NN*HID)
#define BK_OFF  (A_OFF + A_SZ)
#define BK_SZ   (BB*NH*NN*HID)
#define V_OFF   (BK_OFF + BK_SZ)
#define V_SZ    (BB*NH*NN*DH)
#define DEN_OFF (V_OFF + V_SZ)
#define DEN_SZ  (BB*NH*KN*DH)
#define AGG_OFF (DEN_OFF + DEN_SZ)
#define AGG_SZ  (BB*NH*NN*DH)
#define NUM_OFF (AGG_OFF + AGG_SZ)                 // bf16 num buffer: [bh][i][j][d]
#define NUM_ELTS ((size_t)BB*NH*NN*KN*DH)          // 46.3M bf16 = 92.6 MB
#define BHF_OFF (NUM_OFF + NUM_ELTS/2)             // fp16 copy of Bk: [bh][p][e]
#define AHF_OFF (BHF_OFF + BK_SZ/2)                // fp16 copy of A:  [bh][p][e]
#define WS_NEED_BYTES ((size_t)(AHF_OFF + A_SZ/2)*4)

typedef float v2f __attribute__((ext_vector_type(2)));
typedef __attribute__((ext_vector_type(8))) short bf16x8;
typedef __attribute__((ext_vector_type(4))) float f32x4;
typedef _Float16 fp16x8 __attribute__((ext_vector_type(8)));
typedef _Float16 h2 __attribute__((ext_vector_type(2)));
#define SWZ(x, imm) __int_as_float(__builtin_amdgcn_ds_swizzle(__float_as_int(x), imm))

union U16x8 { uint4 q; h2 h[4]; fp16x8 v; };

static __device__ __forceinline__ float bfb(unsigned short u){
    return __uint_as_float(((unsigned)u) << 16);
}
// HW packed convert: dst.lo = bf16(a), dst.hi = bf16(b)
static __device__ __forceinline__ unsigned cvtpk(float a, float b){
    unsigned r;
    asm("v_cvt_pk_bf16_f32 %0, %1, %2" : "=v"(r) : "v"(a), "v"(b));
    return r;
}
static __device__ __forceinline__ unsigned short f2h_bits(float f){
    _Float16 h = (_Float16)f;
    unsigned short u; __builtin_memcpy(&u, &h, 2); return u;
}

// ---------------- K1: qkv = x @ w_qkv ----------------
__global__ void qkv_kernel(const float* __restrict__ x, const float* __restrict__ w_qkv, float* ws){
    int t = blockIdx.x*256 + threadIdx.x;
    if (t >= BB*NN*96) return;
    int c = t % 96;
    int p = (t / 96) % NN;
    int b = t / (96*NN);
    const float* xr = x + (b*NN + p)*DIM;
    float acc = 0.f;
    #pragma unroll 8
    for (int dd=0; dd<DIM; dd++)
        acc = fmaf(xr[dd], w_qkv[dd*96 + c], acc);
    ws[QKV_OFF + (b*NN + p)*96 + c] = acc;
}

// ---------------- K2: A = w1.q + b1 ; Bk = w1.k ; fp16 copies ; V copy ----------------
__global__ void ab_kernel(const float* __restrict__ w1, const float* __restrict__ b1, float* ws){
    int t = blockIdx.x*256 + threadIdx.x;
    if (t >= BB*NH*NN*HID) return;
    int e  = t % HID;
    int p  = (t / HID) % NN;
    int hh = (t / (HID*NN)) % NH;
    int b  = t / (HID*NN*NH);
    const float* qkv = ws + QKV_OFF + (b*NN + p)*96;
    const float* w1r = w1 + (hh*HID + e)*DH;
    float sa = b1[hh*HID + e];
    float sb = 0.f;
    #pragma unroll
    for (int d=0; d<DH; d++){
        float wv = w1r[d];
        sa = fmaf(wv, qkv[hh*DH + d],      sa);
        sb = fmaf(wv, qkv[32 + hh*DH + d], sb);
    }
    int base = ((b*NH + hh)*NN + p);
    ws[A_OFF  + base*HID + e] = sa;
    ws[BK_OFF + base*HID + e] = sb;
    ((unsigned short*)(ws + BHF_OFF))[(size_t)base*HID + e] = f2h_bits(sb);
    ((unsigned short*)(ws + AHF_OFF))[(size_t)base*HID + e] = f2h_bits(sa);
    if (e < DH)
        ws[V_OFF + base*DH + e] = qkv[64 + hh*DH + e];
}

// ---------------- K3 (big path): MFMA pass1, fp16 fragments, 3-deep B prefetch ----------------
// sim^T[d,j] = w2 . relu(A[i]-B[p_j])^T via mfma_f32_16x16x32_f16(w2frag, relufrag, c).
// num[bh][i][j][d] bf16: per-lane 4 d's contiguous -> one uint2 store per i.
// grid (20,12,8) = 1920 blocks (7.5/CU). bh = lin&7 = XCD; jt adjacent in dispatch.
__global__ __launch_bounds__(256) void pass1_mfma(const int* __restrict__ idx,
                                                  const float* __restrict__ w2,
                                                  const float* __restrict__ b2, float* ws){
    int lin = blockIdx.x + 20*(blockIdx.y + 12*blockIdx.z);
    int bh  = lin & 7;
    int rest = lin >> 3;          // 0..239
    int jt  = rest % 20;          // adjacent dispatch => adjacent jt
    int yy  = rest / 20;          // 0..11
    int hh  = bh & (NH-1);
    int w = threadIdx.x >> 6, lane = threadIdx.x & 63;
    int n  = lane & 15;    // MFMA col = j index within tile
    int kg = lane >> 4;    // e-slice group; C rows d = kg*4..+3
    int strip = yy*4 + w;  // 0..47
    int i0 = strip*48;

    const float LG2E = 1.44269504088896340736f;
    U16x8 bfr;   // w2 fragment (A-operand rows d=n), fp16, scaled by log2e
    #pragma unroll
    for (int tt=0; tt<8; tt++){
        float wvv = (n < DH) ? w2[(hh*DH + n)*HID + kg*8 + tt]*LG2E : 0.f;
        bfr.v[tt] = (_Float16)wvv;
    }
    // C-init: row d = kg*4+r gets b2[d]*LG2E (rows >= DH are padding)
    f32x4 cinit;
    #pragma unroll
    for (int r=0; r<4; r++){
        int d = kg*4 + r;
        cinit[r] = (d < DH) ? b2[hh*DH + d]*LG2E : 0.f;
    }

    int jrow = jt*16 + n;                 // this lane's j (B-operand col & C col)
    int jj = jrow < KN ? jrow : (KN-1);
    bool stok = (jrow < KN) && (kg < 2);  // lanes holding real (j,d) results

    const unsigned short* Ahf = (const unsigned short*)(ws + AHF_OFF) + (size_t)bh*NN*HID;
    const unsigned short* Bhf = (const unsigned short*)(ws + BHF_OFF) + (size_t)bh*NN*HID;
    const int* idxp = idx + (size_t)i0*KN + jj;
    const unsigned short* ap = Ahf + (size_t)i0*HID + kg*8;

    unsigned short* numb = (unsigned short*)(ws + NUM_OFF);
    size_t nb = (((size_t)bh*NN + i0)*KN + jj)*DH + kg*4;
    const size_t NPI = (size_t)KN*DH;   // shorts per i

    f32x4 den; den[0]=0.f; den[1]=0.f; den[2]=0.f; den[3]=0.f;
    const h2 zz = { (_Float16)0.f, (_Float16)0.f };

    // pipeline: B three iterations ahead, p four iterations ahead
    int p0 = idxp[0], p1 = idxp[KN]; idxp += 2*KN;           // t=0
    uint4 Bc0 = *(const uint4*)(Bhf + (size_t)p0*HID + kg*8);
    uint4 Bc1 = *(const uint4*)(Bhf + (size_t)p1*HID + kg*8);
    p0 = idxp[0]; p1 = idxp[KN]; idxp += 2*KN;               // t=1
    uint4 Bn0 = *(const uint4*)(Bhf + (size_t)p0*HID + kg*8);
    uint4 Bn1 = *(const uint4*)(Bhf + (size_t)p1*HID + kg*8);
    p0 = idxp[0]; p1 = idxp[KN]; idxp += 2*KN;               // t=2
    uint4 Bm0 = *(const uint4*)(Bhf + (size_t)p0*HID + kg*8);
    uint4 Bm1 = *(const uint4*)(Bhf + (size_t)p1*HID + kg*8);
    p0 = idxp[0]; p1 = idxp[KN]; idxp += 2*KN;               // t=3

    for (int ii=0; ii<48; ii+=2){
        U16x8 Ah0, Ah1;
        Ah0.q = *(const uint4*)ap;
        Ah1.q = *(const uint4*)(ap + HID);
        ap += 2*HID;

        uint4 Bf0 = Bc0, Bf1 = Bc1;
        if (ii < 42){   // load B for iteration t+3
            Bf0 = *(const uint4*)(Bhf + (size_t)p0*HID + kg*8);
            Bf1 = *(const uint4*)(Bhf + (size_t)p1*HID + kg*8);
        }
        if (ii < 40){ p0 = idxp[0]; p1 = idxp[KN]; idxp += 2*KN; }   // p for t+4

        // fp16 packed fragment build: 4 pk_sub + 4 pk_max per i
        U16x8 Bu0, Bu1, af0, af1;
        Bu0.q = Bc0; Bu1.q = Bc1;
        #pragma unroll
        for (int k=0; k<4; k++){
            h2 d0h = Ah0.h[k] - Bu0.h[k];
            af0.h[k] = __builtin_elementwise_max(d0h, zz);
            h2 d1h = Ah1.h[k] - Bu1.h[k];
            af1.h[k] = __builtin_elementwise_max(d1h, zz);
        }

        // swapped operands: D[d, j] = w2 x relu^T + C
        f32x4 d0 = __builtin_amdgcn_mfma_f32_16x16x32_f16(bfr.v, af0.v, cinit, 0, 0, 0);
        f32x4 d1 = __builtin_amdgcn_mfma_f32_16x16x32_f16(bfr.v, af1.v, cinit, 0, 0, 0);

        float e00 = exp2f(d0[0]), e01 = exp2f(d0[1]), e02 = exp2f(d0[2]), e03 = exp2f(d0[3]);
        float e10 = exp2f(d1[0]), e11 = exp2f(d1[1]), e12 = exp2f(d1[2]), e13 = exp2f(d1[3]);
        den[0] += e00 + e10; den[1] += e01 + e11;
        den[2] += e02 + e12; den[3] += e03 + e13;

        // one uint2 (4 bf16 d-values) store per i per lane
        if (stok){
            uint2 s0; s0.x = cvtpk(e00, e01); s0.y = cvtpk(e02, e03);
            uint2 s1; s1.x = cvtpk(e10, e11); s1.y = cvtpk(e12, e13);
            *(uint2*)(numb + nb)       = s0;
            *(uint2*)(numb + nb + NPI) = s1;
        }
        nb += 2*NPI;

        Bc0 = Bn0; Bc1 = Bn1; Bn0 = Bm0; Bn1 = Bm1; Bm0 = Bf0; Bm1 = Bf1;
    }

    if (stok){
        float* denp = ws + DEN_OFF + ((size_t)bh*KN + jrow)*DH + kg*4;
        #pragma unroll
        for (int r2=0; r2<4; r2++)
            atomicAdd(denp + r2, den[r2]);
    }
}

// ---------------- K3.5 (small path only): invert den in place ----------------
__global__ void invden_kernel(float* ws){
    int t = blockIdx.x*256 + threadIdx.x;
    if (t < DEN_SZ){
        float* d = ws + DEN_OFF;
        d[t] = 1.0f / d[t];
    }
}

// ---------------- K4-fast: agg[i,d] = sum_j num[i,j,d]*inv(den[j,d])*v[p,d] ----------------
// grid: (288, NH, BB); block 256 = 4 waves, 2 i per wave (round-13 proven form)
__global__ __launch_bounds__(256) void pass2f_kernel(const int* __restrict__ idx, float* ws){
    int hh = blockIdx.y, b = blockIdx.z;
    int w = threadIdx.x >> 6, lane = threadIdx.x & 63;
    int g = lane >> 3, dd = lane & 7;
    int bh = b*NH + hh;

    __shared__ float invs[KN*DH];
    {
        const float* den = ws + DEN_OFF + (size_t)bh*KN*DH;
        for (int t = threadIdx.x; t < KN*DH; t += 256) invs[t] = 1.0f / den[t];
    }
    __syncthreads();

    const float* Vbuf = ws + V_OFF + (size_t)bh*NN*DH;
    float* agg = ws + AGG_OFF + (size_t)bh*NN*DH;

    int i0 = blockIdx.x*8 + w*2;
    const unsigned short* num0 = (const unsigned short*)(ws + NUM_OFF)
                                 + ((size_t)bh*NN + i0)*KN*DH + dd;
    const unsigned short* num1 = num0 + (size_t)KN*DH;
    const int* ix0 = idx + (size_t)i0*KN;
    const int* ix1 = ix0 + KN;

    int p0 = ix0[g], p1 = ix1[g];
    float m0 = bfb(num0[g*DH]), m1 = bfb(num1[g*DH]);
    float acc0 = 0.f, acc1 = 0.f;

    for (int sg=0; sg<40; sg++){
        int jc = sg*8 + g;
        int jcc = jc < KN ? jc : (KN-1);
        float v0 = Vbuf[(size_t)p0*DH + dd];
        float v1 = Vbuf[(size_t)p1*DH + dd];
        float iv = invs[jcc*DH + dd];
        float w0 = m0 * iv, w1 = m1 * iv;
        if (jc >= KN){ w0 = 0.f; w1 = 0.f; }
        if (sg < 39){
            int jn = jc + 8; int jjn = jn < KN ? jn : (KN-1);
            p0 = ix0[jjn]; p1 = ix1[jjn];
            m0 = bfb(num0[(size_t)jjn*DH]);
            m1 = bfb(num1[(size_t)jjn*DH]);
        }
        acc0 = fmaf(w0, v0, acc0);
        acc1 = fmaf(w1, v1, acc1);
    }
    acc0 += __shfl_xor(acc0, 8, 64);
    acc0 += __shfl_xor(acc0, 16, 64);
    acc0 += __shfl_xor(acc0, 32, 64);
    acc1 += __shfl_xor(acc1, 8, 64);
    acc1 += __shfl_xor(acc1, 16, 64);
    acc1 += __shfl_xor(acc1, 32, 64);
    if (g == 0){
        agg[(size_t)i0*DH + dd]     = acc0;
        agg[(size_t)(i0+1)*DH + dd] = acc1;
    }
}

// ================= fallback path (small ws): proven VALU kernels =================
__device__ __forceinline__ void load_w2p(const float* __restrict__ w2, int hh, int dd,
                                         v2f w2a[8], v2f w2b[8]){
    #pragma unroll
    for (int m=0; m<8; m++){
        int d = dd ^ (((m&1)<<2) | (m&2) | ((m>>2)&1));
        const float* wp = w2 + (hh*DH + d)*HID + 4*dd;
        v2f a; a.x = wp[0]; a.y = wp[1];
        v2f b; b.x = wp[2]; b.y = wp[3];
        w2a[m] = a; w2b[m] = b;
    }
}
__device__ __forceinline__ float butterfly8p(float pr[8]){
    float q0 = pr[0] + SWZ(pr[4], 0x041F);
    float q1 = pr[1] + SWZ(pr[5], 0x041F);
    float q2 = pr[2] + SWZ(pr[6], 0x041F);
    float q3 = pr[3] + SWZ(pr[7], 0x041F);
    float r0 = q0 + SWZ(q2, 0x081F);
    float r1 = q1 + SWZ(q3, 0x081F);
    return r0 + SWZ(r1, 0x101F);
}
__global__ __launch_bounds__(256, 4) void pass1_small(const int* __restrict__ idx,
                                                      const float* __restrict__ w2,
                                                      const float* __restrict__ b2, float* ws){
    int sgic = blockIdx.x, hh = blockIdx.y, b = blockIdx.z;
    int sg = sgic >> 4, ic = sgic & 15;
    int w = threadIdx.x >> 6, lane = threadIdx.x & 63;
    int g = lane >> 3, dd = lane & 7;
    int j = sg*8 + g;
    bool jv = (j < KN);
    int jj = jv ? j : (KN-1);
    int bh = b*NH + hh;

    v2f w2a[8], w2b[8];
    load_w2p(w2, hh, dd, w2a, w2b);
    float b2v = b2[hh*DH + dd];

    const float* Abuf = ws + A_OFF  + (size_t)bh*NN*HID + 4*dd;
    const float* Bbuf = ws + BK_OFF + (size_t)bh*NN*HID + 4*dd;
    const int* idxc = idx + jj;

    float den_acc = 0.f;
    int i0 = ic*144 + w*36;
    for (int ii=0; ii<36; ii++){
        int i = i0 + ii;
        int p = idxc[(size_t)i*KN];
        float4 avv = *(const float4*)(Abuf + (size_t)i*HID);
        float4 bvv = *(const float4*)(Bbuf + (size_t)p*HID);
        v2f a0; a0.x=avv.x; a0.y=avv.y;
        v2f a1; a1.x=avv.z; a1.y=avv.w;
        v2f c0; c0.x=bvv.x; c0.y=bvv.y;
        v2f c1; c1.x=bvv.z; c1.y=bvv.w;
        v2f z;  z.x=0.f; z.y=0.f;
        v2f r0 = __builtin_elementwise_max(a0-c0, z);
        v2f r1 = __builtin_elementwise_max(a1-c1, z);
        float pr[8];
        #pragma unroll
        for (int m=0; m<8; m++){
            v2f t = w2a[m]*r0;
            t = __builtin_elementwise_fma(w2b[m], r1, t);
            pr[m] = t.x + t.y;
        }
        float sim = butterfly8p(pr) + b2v;
        den_acc += __expf(sim);
    }
    if (!jv) den_acc = 0.f;

    __shared__ float red[256];
    red[threadIdx.x] = den_acc;
    __syncthreads();
    if (w == 0 && jv){
        float s = red[lane] + red[lane+64] + red[lane+128] + red[lane+192];
        atomicAdd(ws + DEN_OFF + ((size_t)bh*KN + j)*DH + dd, s);
    }
}
__device__ __forceinline__ void load_w2s(const float* __restrict__ w2, int hh, int dd, float w2s[8][4]){
    #pragma unroll
    for (int m=0; m<8; m++){
        int d = ((m&1)<<2) | (m&2) | ((m>>2)&1);
        const float* wp = w2 + (hh*DH + d)*HID + 4*dd;
        w2s[m][0]=wp[0]; w2s[m][1]=wp[1]; w2s[m][2]=wp[2]; w2s[m][3]=wp[3];
    }
}
__device__ __forceinline__ float butterfly8(float pr[8], int dd){
    int b0 = dd&1, b1 = (dd>>1)&1, b2b = (dd>>2)&1;
    float q[4];
    #pragma unroll
    for (int t=0; t<4; t++){
        float send = pr[4*(1-b0)+t];
        float recv = __shfl_xor(send, 1, 64);
        q[t] = pr[4*b0+t] + recv;
    }
    float r[2];
    #pragma unroll
    for (int t=0; t<2; t++){
        float send = q[2*(1-b1)+t];
        float recv = __shfl_xor(send, 2, 64);
        r[t] = q[2*b1+t] + recv;
    }
    float send = r[1-b2b];
    float recv = __shfl_xor(send, 4, 64);
    return r[b2b] + recv;
}
__global__ __launch_bounds__(256) void pass2_kernel(const int* __restrict__ idx,
                                                    const float* __restrict__ w2,
                                                    const float* __restrict__ b2, float* ws){
    int ic = blockIdx.x, hh = blockIdx.y, b = blockIdx.z;
    int w = threadIdx.x >> 6, lane = threadIdx.x & 63;
    int g = lane >> 3, dd = lane & 7;

    float w2s[8][4];
    load_w2s(w2, hh, dd, w2s);
    float b2v = b2[hh*DH + dd];

    const float* Abuf = ws + A_OFF  + (size_t)(b*NH + hh)*NN*HID;
    const float* Bbuf = ws + BK_OFF + (size_t)(b*NH + hh)*NN*HID;
    const float* Vbuf = ws + V_OFF  + (size_t)(b*NH + hh)*NN*DH;
    const float* invd = ws + DEN_OFF + (size_t)(b*NH + hh)*KN*DH;
    float*       agg  = ws + AGG_OFF + (size_t)(b*NH + hh)*NN*DH;

    int i0 = ic*8 + w*2;
    #pragma unroll
    for (int ii=0; ii<2; ii++){
        int i = i0 + ii;
        float4 av = *(const float4*)(Abuf + (size_t)i*HID + 4*dd);
        float acc = 0.f;
        for (int sg=0; sg<40; sg++){
            int j = sg*8 + g;
            bool jvv = (j < KN);
            int jj = jvv ? j : (KN-1);
            int p = idx[i*KN + jj];
            float4 bv = *(const float4*)(Bbuf + (size_t)p*HID + 4*dd);
            float r0 = fmaxf(av.x-bv.x, 0.f), r1 = fmaxf(av.y-bv.y, 0.f);
            float r2 = fmaxf(av.z-bv.z, 0.f), r3 = fmaxf(av.w-bv.w, 0.f);
            float pr[8];
            #pragma unroll
            for (int m=0; m<8; m++)
                pr[m] = fmaf(w2s[m][0],r0, fmaf(w2s[m][1],r1, fmaf(w2s[m][2],r2, w2s[m][3]*r3)));
            float sim = butterfly8(pr, dd) + b2v;
            float attn = jvv ? (__expf(sim) * invd[(size_t)jj*DH + dd]) : 0.f;
            acc = fmaf(attn, Vbuf[(size_t)p*DH + dd], acc);
        }
        acc += __shfl_xor(acc, 8, 64);
        acc += __shfl_xor(acc, 16, 64);
        acc += __shfl_xor(acc, 32, 64);
        if (g == 0) agg[(size_t)i*DH + dd] = acc;
    }
}

// ---------------- K5: out = agg @ w_out + b_out ----------------
__global__ void out_kernel(const float* __restrict__ w_out, const float* __restrict__ b_out,
                           const float* __restrict__ ws, float* __restrict__ out){
    int t = blockIdx.x*256 + threadIdx.x;
    if (t >= BB*NN*DIM) return;
    int c = t % DIM;
    int p = (t / DIM) % NN;
    int b = t / (DIM*NN);
    const float* agg = ws + AGG_OFF;
    float s = b_out[c];
    #pragma unroll
    for (int f=0; f<32; f++){
        int hh = f >> 3, d = f & 7;
        s = fmaf(agg[(((size_t)(b*NH + hh)*NN) + p)*DH + d], w_out[f*DIM + c], s);
    }
    out[t] = s;
}

extern "C" void kernel_launch(void* const* d_in, const int* in_sizes, int n_in,
                              void* d_out, int out_size, void* d_ws, size_t ws_size,
                              hipStream_t stream){
    const float* x     = (const float*)d_in[0];
    const int*   idx   = (const int*)d_in[1];
    const float* w_qkv = (const float*)d_in[2];
    const float* w1    = (const float*)d_in[3];
    const float* b1    = (const float*)d_in[4];
    const float* w2    = (const float*)d_in[5];
    const float* b2    = (const float*)d_in[6];
    const float* w_out = (const float*)d_in[7];
    const float* b_out = (const float*)d_in[8];
    float* ws  = (float*)d_ws;
    float* out = (float*)d_out;

    bool big = (ws_size >= WS_NEED_BYTES);

    hipMemsetAsync(ws + DEN_OFF, 0, DEN_SZ*sizeof(float), stream);

    qkv_kernel<<<(BB*NN*96 + 255)/256, 256, 0, stream>>>(x, w_qkv, ws);
    ab_kernel <<<(BB*NH*NN*HID + 255)/256, 256, 0, stream>>>(w1, b1, ws);
    if (big){
        pass1_mfma<<<dim3(20, 12, 8), 256, 0, stream>>>(idx, w2, b2, ws);
        pass2f_kernel<<<dim3(288, NH, BB), 256, 0, stream>>>(idx, ws);
    } else {
        pass1_small<<<dim3(640, NH, BB), 256, 0, stream>>>(idx, w2, b2, ws);
        invden_kernel<<<(DEN_SZ + 255)/256, 256, 0, stream>>>(ws);
        pass2_kernel<<<dim3(288, NH, BB), 256, 0, stream>>>(idx, w2, b2, ws);
    }
    out_kernel<<<(BB*NN*DIM + 255)/256, 256, 0, stream>>>(w_out, b_out, ws, out);
}